// Round 1
// baseline (1131.669 us; speedup 1.0000x reference)
//
#include <hip/hip_runtime.h>

#define N_NODES 100000
#define N_EDGES 1600000
#define FEATS 48

// 12 threads per edge, each handling a float4 (4 feats). Accumulate sums
// in-place into d_out, degrees into d_ws.
__global__ void gnn_scatter_kernel(const float4* __restrict__ feat4,
                                   const int* __restrict__ src,
                                   const int* __restrict__ dst,
                                   float* __restrict__ sums,
                                   float* __restrict__ deg) {
    long long i = (long long)blockIdx.x * blockDim.x + threadIdx.x;
    const long long total = (long long)N_EDGES * 12;
    if (i >= total) return;
    int e = (int)(i / 12);
    int q = (int)(i - (long long)e * 12);
    int s = src[e];
    int d = dst[e];
    float4 v = feat4[s * 12 + q];
    float* p = sums + d * FEATS + q * 4;
    atomicAdd(p + 0, v.x);
    atomicAdd(p + 1, v.y);
    atomicAdd(p + 2, v.z);
    atomicAdd(p + 3, v.w);
    if (q == 0) atomicAdd(deg + d, 1.0f);
}

// One block (64 threads) per node. Stage the summed row in LDS (so all
// reads of the row complete before we overwrite it in-place), then apply
// mean + linear: out[n,o] = sum_f (sums[n,f]/max(deg,1)) * W[o,f] + b[o].
__global__ void gnn_finish_kernel(float* __restrict__ out,
                                  const float* __restrict__ deg,
                                  const float* __restrict__ W,
                                  const float* __restrict__ b) {
    __shared__ float mean[FEATS];
    int n = blockIdx.x;
    int t = threadIdx.x;
    if (t < FEATS) {
        float dn = deg[n];
        mean[t] = out[n * FEATS + t] / fmaxf(dn, 1.0f);
    }
    __syncthreads();
    if (t < FEATS) {
        float acc = b[t];
        const float* wr = W + t * FEATS;
#pragma unroll
        for (int f = 0; f < FEATS; ++f) acc += mean[f] * wr[f];
        out[n * FEATS + t] = acc;
    }
}

extern "C" void kernel_launch(void* const* d_in, const int* in_sizes, int n_in,
                              void* d_out, int out_size, void* d_ws, size_t ws_size,
                              hipStream_t stream) {
    const float* feature = (const float*)d_in[0];
    const float* W       = (const float*)d_in[1];
    const float* b       = (const float*)d_in[2];
    const int*   src     = (const int*)d_in[3];
    const int*   dst     = (const int*)d_in[4];

    float* out = (float*)d_out;        // doubles as the sum accumulator
    float* deg = (float*)d_ws;         // N_NODES floats of scratch

    hipMemsetAsync(out, 0, (size_t)N_NODES * FEATS * sizeof(float), stream);
    hipMemsetAsync(deg, 0, (size_t)N_NODES * sizeof(float), stream);

    const long long total = (long long)N_EDGES * 12;
    int blocks = (int)((total + 255) / 256);
    gnn_scatter_kernel<<<blocks, 256, 0, stream>>>(
        (const float4*)feature, src, dst, out, deg);

    gnn_finish_kernel<<<N_NODES, 64, 0, stream>>>(out, deg, W, b);
}

// Round 2
// 321.819 us; speedup vs baseline: 3.5165x; 3.5165x over previous
//
#include <hip/hip_runtime.h>

#define N_NODES 100000
#define N_EDGES 1600000
#define FEATS 48

// ---------------- CSR-build path (fast) ----------------

__global__ void count_kernel(const int* __restrict__ dst, int* __restrict__ cnt) {
    int e = blockIdx.x * blockDim.x + threadIdx.x;
    if (e < N_EDGES) atomicAdd(&cnt[dst[e]], 1);
}

// Wave-level exclusive scan of counts + one atomic per wave on a global cursor.
// Layout of node segments in eid[] is race-dependent but forms a valid partition.
__global__ void offsets_kernel(const int* __restrict__ cnt, int* __restrict__ gcounter,
                               int* __restrict__ off, int* __restrict__ cur) {
    int n = blockIdx.x * blockDim.x + threadIdx.x;
    int lane = threadIdx.x & 63;
    int c = (n < N_NODES) ? cnt[n] : 0;
    int incl = c;
#pragma unroll
    for (int d = 1; d < 64; d <<= 1) {
        int v = __shfl_up(incl, d);
        if (lane >= d) incl += v;
    }
    int wtot = __shfl(incl, 63);
    int base = 0;
    if (lane == 63) base = atomicAdd(gcounter, wtot);
    base = __shfl(base, 63);
    int o = base + incl - c;
    if (n < N_NODES) { off[n] = o; cur[n] = o; }
}

__global__ void scatter_kernel(const int* __restrict__ src, const int* __restrict__ dst,
                               int* __restrict__ cur, int* __restrict__ eid) {
    int e = blockIdx.x * blockDim.x + threadIdx.x;
    if (e < N_EDGES) {
        int p = atomicAdd(&cur[dst[e]], 1);
        eid[p] = src[e];
    }
}

// One wave per node: gather+sum feature rows (coalesced 192B reads, L2/L3-hit),
// then fused mean + linear epilogue with LDS-staged W^T.
__global__ __launch_bounds__(256) void gather_kernel(
    const float* __restrict__ feature,
    const int* __restrict__ cnt, const int* __restrict__ off,
    const int* __restrict__ eid,
    const float* __restrict__ W, const float* __restrict__ b,
    float* __restrict__ out) {
    __shared__ float Wt[FEATS * FEATS];   // Wt[f*48+o] = W[o*48+f] -> lane-o reads conflict-free
    __shared__ float meanS[4][FEATS];
    int tid = threadIdx.x;
    for (int i = tid; i < FEATS * FEATS; i += 256) {
        int o = i / FEATS, f = i - o * FEATS;
        Wt[f * FEATS + o] = W[i];
    }
    __syncthreads();

    int wave = tid >> 6, lane = tid & 63;
    int n = blockIdx.x * 4 + wave;
    if (n >= N_NODES) return;
    int c = cnt[n];
    int o = off[n];

    if (lane < FEATS) {
        float acc = 0.f;
        int t = lane;
        int i = 0;
        for (; i + 4 <= c; i += 4) {  // unroll-4: overlap eid + feature loads
            int s0 = eid[o + i], s1 = eid[o + i + 1], s2 = eid[o + i + 2], s3 = eid[o + i + 3];
            acc += feature[s0 * FEATS + t];
            acc += feature[s1 * FEATS + t];
            acc += feature[s2 * FEATS + t];
            acc += feature[s3 * FEATS + t];
        }
        for (; i < c; ++i) {
            int s = eid[o + i];
            acc += feature[s * FEATS + t];
        }
        meanS[wave][t] = acc / fmaxf((float)c, 1.0f);
        // same-wave LDS write->read is in-order; no cross-wave sharing -> no barrier
        float r = b[t];
#pragma unroll
        for (int f = 0; f < FEATS; ++f)
            r += meanS[wave][f] * Wt[f * FEATS + t];
        out[n * FEATS + t] = r;
    }
}

// ---------------- fallback path (R1 atomics) if ws too small ----------------

__global__ void gnn_scatter_atomic(const float4* __restrict__ feat4,
                                   const int* __restrict__ src,
                                   const int* __restrict__ dst,
                                   float* __restrict__ sums,
                                   float* __restrict__ deg) {
    long long i = (long long)blockIdx.x * blockDim.x + threadIdx.x;
    const long long total = (long long)N_EDGES * 12;
    if (i >= total) return;
    int e = (int)(i / 12);
    int q = (int)(i - (long long)e * 12);
    int s = src[e];
    int d = dst[e];
    float4 v = feat4[s * 12 + q];
    float* p = sums + d * FEATS + q * 4;
    atomicAdd(p + 0, v.x);
    atomicAdd(p + 1, v.y);
    atomicAdd(p + 2, v.z);
    atomicAdd(p + 3, v.w);
    if (q == 0) atomicAdd(deg + d, 1.0f);
}

__global__ void gnn_finish_atomic(float* __restrict__ out,
                                  const float* __restrict__ deg,
                                  const float* __restrict__ W,
                                  const float* __restrict__ b) {
    __shared__ float mean[FEATS];
    int n = blockIdx.x;
    int t = threadIdx.x;
    if (t < FEATS) {
        float dn = deg[n];
        mean[t] = out[n * FEATS + t] / fmaxf(dn, 1.0f);
    }
    __syncthreads();
    if (t < FEATS) {
        float acc = b[t];
        const float* wr = W + t * FEATS;
#pragma unroll
        for (int f = 0; f < FEATS; ++f) acc += mean[f] * wr[f];
        out[n * FEATS + t] = acc;
    }
}

extern "C" void kernel_launch(void* const* d_in, const int* in_sizes, int n_in,
                              void* d_out, int out_size, void* d_ws, size_t ws_size,
                              hipStream_t stream) {
    const float* feature = (const float*)d_in[0];
    const float* W       = (const float*)d_in[1];
    const float* b       = (const float*)d_in[2];
    const int*   src     = (const int*)d_in[3];
    const int*   dst     = (const int*)d_in[4];
    float* out = (float*)d_out;

    // ws layout (ints): cnt[N] | gcounter[1] | off[N] | cur[N] | eid[E]
    const size_t needed = ((size_t)3 * N_NODES + 1 + N_EDGES) * sizeof(int);

    if (ws_size >= needed) {
        int* I = (int*)d_ws;
        int* cnt = I;
        int* gcounter = I + N_NODES;
        int* off = I + N_NODES + 1;
        int* cur = off + N_NODES;
        int* eid = cur + N_NODES;

        hipMemsetAsync(cnt, 0, (size_t)(N_NODES + 1) * sizeof(int), stream);

        int eb = (N_EDGES + 255) / 256;
        count_kernel<<<eb, 256, 0, stream>>>(dst, cnt);
        int nb = (N_NODES + 255) / 256;
        offsets_kernel<<<nb, 256, 0, stream>>>(cnt, gcounter, off, cur);
        scatter_kernel<<<eb, 256, 0, stream>>>(src, dst, cur, eid);
        gather_kernel<<<(N_NODES + 3) / 4, 256, 0, stream>>>(feature, cnt, off, eid, W, b, out);
    } else {
        float* deg = (float*)d_ws;
        hipMemsetAsync(out, 0, (size_t)N_NODES * FEATS * sizeof(float), stream);
        hipMemsetAsync(deg, 0, (size_t)N_NODES * sizeof(float), stream);
        const long long total = (long long)N_EDGES * 12;
        int blocks = (int)((total + 255) / 256);
        gnn_scatter_atomic<<<blocks, 256, 0, stream>>>((const float4*)feature, src, dst, out, deg);
        gnn_finish_atomic<<<N_NODES, 64, 0, stream>>>(out, deg, W, b);
    }
}